// Round 1
// baseline (408.024 us; speedup 1.0000x reference)
//
#include <hip/hip_runtime.h>

#define T_    1024
#define H_    1024
#define IDIM  1024
#define E_    16
#define TOPK  4
#define ALPHA 1.702f
#define LIMIT 7.0f

typedef __bf16 bf16;
typedef __bf16 bf16x4 __attribute__((ext_vector_type(4)));
typedef __bf16 bf16x8 __attribute__((ext_vector_type(8)));
typedef float  f32x4  __attribute__((ext_vector_type(4)));

// ---------------------------------------------------------------------------
// Kernel 1: RMSNorm + router logits + softmax/top-4 + routing lists.
// Also writes out = x (residual init) and t in bf16 for the MFMA GEMMs.
// One block (256 thr) per token.
// ---------------------------------------------------------------------------
__global__ __launch_bounds__(256) void k_rms_router(
    const float* __restrict__ x, const float* __restrict__ nw,
    const float* __restrict__ rw, const float* __restrict__ rb,
    const float* __restrict__ mw, const int* __restrict__ lidx,
    bf16* __restrict__ tB, float* __restrict__ out,
    int* __restrict__ cnt, int* __restrict__ tok_list,
    float* __restrict__ wgt_list)
{
    const int t = blockIdx.x, tid = threadIdx.x;
    const int lane = tid & 63, wave = tid >> 6;
    __shared__ float tbuf[H_];
    __shared__ float red[4];
    __shared__ float logits[E_];

    float4 xv = ((const float4*)(x + (size_t)t * H_))[tid];
    float4 wv = ((const float4*)nw)[tid];
    float ssq = xv.x*xv.x + xv.y*xv.y + xv.z*xv.z + xv.w*xv.w;
    #pragma unroll
    for (int off = 32; off; off >>= 1) ssq += __shfl_xor(ssq, off);
    if (lane == 0) red[wave] = ssq;
    __syncthreads();
    const float rms = rsqrtf((red[0] + red[1] + red[2] + red[3]) * (1.0f / H_) + 1e-5f);

    float4 tv;
    tv.x = xv.x * rms * wv.x;
    tv.y = xv.y * rms * wv.y;
    tv.z = xv.z * rms * wv.z;
    tv.w = xv.w * rms * wv.w;

    ((float4*)(out + (size_t)t * H_))[tid] = xv;      // residual init
    ((float4*)tbuf)[tid] = tv;                        // fp32 t for router
    bf16x4 tb = { (bf16)tv.x, (bf16)tv.y, (bf16)tv.z, (bf16)tv.w };
    *(bf16x4*)(tB + (size_t)t * H_ + tid * 4) = tb;   // bf16 t for GEMMs
    __syncthreads();

    // Router: wave w computes experts 4w..4w+3 (dot over H=1024).
    #pragma unroll
    for (int ei = 0; ei < 4; ++ei) {
        const int e = wave * 4 + ei;
        const float* wr = rw + (size_t)e * H_;
        float s = 0.f;
        #pragma unroll
        for (int j = 0; j < 16; ++j) {
            const int c = lane + j * 64;
            s += tbuf[c] * wr[c];
        }
        #pragma unroll
        for (int off = 32; off; off >>= 1) s += __shfl_xor(s, off);
        if (lane == 0) logits[e] = s + rb[e];
    }
    __syncthreads();

    if (tid == 0) {
        float g[E_];
        #pragma unroll
        for (int e = 0; e < E_; ++e) g[e] = logits[e];

        // conditional manual logit override (inactive when manual_weights == 0)
        const int li = lidx[0];
        float ma = 0.f, lw[E_];
        #pragma unroll
        for (int e = 0; e < E_; ++e) { lw[e] = mw[li * E_ + e]; ma = fmaxf(ma, fabsf(lw[e])); }
        if (ma > 0.f) {
            float mx = -1e30f;
            for (int e = 0; e < E_; ++e) mx = fmaxf(mx, g[e]);
            float se = 0.f;
            for (int e = 0; e < E_; ++e) se += expf(g[e] - mx);
            const float lse = logf(se) + mx;
            float gl[E_], gmx = -1e30f, gmn = 1e30f;
            for (int e = 0; e < E_; ++e) { gl[e] = g[e] - lse; gmx = fmaxf(gmx, gl[e]); gmn = fminf(gmn, gl[e]); }
            for (int e = 0; e < E_; ++e) {
                if (lw[e] > 0.f)      gl[e] = gmx + 0.01f;
                else if (lw[e] < 0.f) gl[e] = gmn - 0.01f;
                g[e] = gl[e];
            }
        }

        // softmax -> top-4 (first-index tiebreak, matches lax.top_k) -> renorm
        float mx = -1e30f;
        #pragma unroll
        for (int e = 0; e < E_; ++e) mx = fmaxf(mx, g[e]);
        float p[E_];
        #pragma unroll
        for (int e = 0; e < E_; ++e) p[e] = expf(g[e] - mx);

        bool used[E_] = {};
        int   idx[TOPK];
        float twv[TOPK];
        float ssum = 0.f;
        for (int k = 0; k < TOPK; ++k) {
            int best = -1; float bv = -1e30f;
            for (int e = 0; e < E_; ++e)
                if (!used[e] && p[e] > bv) { bv = p[e]; best = e; }
            used[best] = true; idx[k] = best; twv[k] = bv; ssum += bv;
        }
        const float inv = 1.f / ssum;
        for (int k = 0; k < TOPK; ++k) {
            const int e = idx[k];
            const int slot = atomicAdd(&cnt[e], 1);
            tok_list[e * T_ + slot] = t;
            wgt_list[e * T_ + slot] = twv[k] * inv;
        }
    }
}

// ---------------------------------------------------------------------------
// Kernel 2: exclusive scan of the 16 expert counts -> base offsets.
// ---------------------------------------------------------------------------
__global__ void k_scan(const int* __restrict__ cnt, int* __restrict__ base)
{
    if (threadIdx.x == 0) {
        int s = 0;
        for (int e = 0; e < E_; ++e) { base[e] = s; s += cnt[e]; }
        base[E_] = s;
    }
}

// ---------------------------------------------------------------------------
// Kernel 3: grouped gate_up GEMM + SwiGLU-OAI activation -> act (bf16).
// Block = 256 thr (2x2 waves), tile BM=64 x BN=64 gate cols (+ matching up
// cols), BK=32, MFMA 16x16x32 bf16. A rows gathered via token list.
// grid = (IDIM/64, T_/64, E_); blocks with m0 >= n_e exit early.
// ---------------------------------------------------------------------------
__global__ __launch_bounds__(256) void k_gateup(
    const bf16* __restrict__ tB, const float* __restrict__ w13,
    const float* __restrict__ b13, const int* __restrict__ cnt,
    const int* __restrict__ base, const int* __restrict__ tok_list,
    bf16* __restrict__ act)
{
    const int e  = blockIdx.z;
    const int ne = cnt[e];
    const int m0 = blockIdx.y * 64;
    if (m0 >= ne) return;
    const int n0  = blockIdx.x * 64;           // gate column base in [0, IDIM)
    const int tid = threadIdx.x, lane = tid & 63, wave = tid >> 6;

    __shared__ __align__(16) bf16 As[64][40];  // [m][k], pad 40 (80B stride)
    __shared__ __align__(16) bf16 Bg[64][40];  // [n][k]
    __shared__ __align__(16) bf16 Bu[64][40];  // [n][k]
    __shared__ int stok[64];

    if (tid < 64) {
        const int s = m0 + tid;
        stok[tid] = (s < ne) ? tok_list[e * T_ + s] : -1;
    }
    __syncthreads();

    // A staging coords: row = tid>>2 (0..63), k-chunk = (tid&3)*8
    const int ar = tid >> 2, ak = (tid & 3) * 8;
    const int atok = stok[ar];
    // B staging coords: n = tid&63 (coalesced), k-chunk = wave*8
    const int bn = tid & 63, bk = wave * 8;
    const size_t wrow = (size_t)(2 * IDIM);    // w13 row stride (over h)
    const float* wbase = w13 + (size_t)e * H_ * wrow + n0 + bn;

    const int wm = wave >> 1, wn = wave & 1;   // 2x2 wave grid, 32x32 each
    const int q = lane >> 4, r = lane & 15;
    f32x4 accg[2][2] = {};
    f32x4 accu[2][2] = {};

    for (int kb = 0; kb < H_ / 32; ++kb) {
        __syncthreads();
        // --- stage A (gathered rows of t, already bf16) ---
        uint4 av = make_uint4(0u, 0u, 0u, 0u);
        if (atok >= 0)
            av = *(const uint4*)(tB + (size_t)atok * H_ + kb * 32 + ak);
        *(uint4*)&As[ar][ak] = av;
        // --- stage B: gate + up, fp32 -> bf16, k-strided dword loads,
        //     one conflict-free ds_write_b128 per tile per thread ---
        {
            const float* src = wbase + (size_t)(kb * 32 + bk) * wrow;
            bf16x8 pg, pu;
            #pragma unroll
            for (int j = 0; j < 8; ++j) {
                pg[j] = (bf16)src[(size_t)j * wrow];
                pu[j] = (bf16)src[(size_t)j * wrow + IDIM];
            }
            *(bf16x8*)&Bg[bn][bk] = pg;
            *(bf16x8*)&Bu[bn][bk] = pu;
        }
        __syncthreads();
        // --- compute: 8 MFMAs (2 a-frags x 2 n-frags x {gate,up}) ---
        bf16x8 a[2], bg[2], bu[2];
        a[0]  = *(const bf16x8*)&As[wm * 32 +      r][q * 8];
        a[1]  = *(const bf16x8*)&As[wm * 32 + 16 + r][q * 8];
        bg[0] = *(const bf16x8*)&Bg[wn * 32 +      r][q * 8];
        bg[1] = *(const bf16x8*)&Bg[wn * 32 + 16 + r][q * 8];
        bu[0] = *(const bf16x8*)&Bu[wn * 32 +      r][q * 8];
        bu[1] = *(const bf16x8*)&Bu[wn * 32 + 16 + r][q * 8];
        #pragma unroll
        for (int im = 0; im < 2; ++im)
            #pragma unroll
            for (int in = 0; in < 2; ++in) {
                accg[im][in] = __builtin_amdgcn_mfma_f32_16x16x32_bf16(a[im], bg[in], accg[im][in], 0, 0, 0);
                accu[im][in] = __builtin_amdgcn_mfma_f32_16x16x32_bf16(a[im], bu[in], accu[im][in], 0, 0, 0);
            }
    }

    // --- epilogue: h = acc + b13; SwiGLU-OAI; store act bf16 ---
    const int sb = base[e];
    #pragma unroll
    for (int im = 0; im < 2; ++im) {
        #pragma unroll
        for (int in = 0; in < 2; ++in) {
            #pragma unroll
            for (int rg = 0; rg < 4; ++rg) {
                const int row = wm * 32 + im * 16 + q * 4 + rg;
                const int col = wn * 32 + in * 16 + r;
                if (m0 + row < ne) {
                    const float hg = accg[im][in][rg] + b13[e * 2 * IDIM + n0 + col];
                    const float hu = accu[im][in][rg] + b13[e * 2 * IDIM + IDIM + n0 + col];
                    const float gt = fminf(hg, LIMIT);
                    const float up = fminf(fmaxf(hu, -LIMIT), LIMIT);
                    const float av = (up + 1.0f) * gt / (1.0f + expf(-ALPHA * gt));
                    act[(size_t)(sb + m0 + row) * IDIM + n0 + col] = (bf16)av;
                }
            }
        }
    }
}

// ---------------------------------------------------------------------------
// Kernel 4: grouped down GEMM + weighted atomic combine into out (fp32).
// Same tiling as k_gateup; A = compact act rows (no gather needed).
// ---------------------------------------------------------------------------
__global__ __launch_bounds__(256) void k_down(
    const bf16* __restrict__ act, const float* __restrict__ w2,
    const float* __restrict__ b2, const int* __restrict__ cnt,
    const int* __restrict__ base, const int* __restrict__ tok_list,
    const float* __restrict__ wgt_list, float* __restrict__ out)
{
    const int e  = blockIdx.z;
    const int ne = cnt[e];
    const int m0 = blockIdx.y * 64;
    if (m0 >= ne) return;
    const int n0  = blockIdx.x * 64;           // h column base
    const int tid = threadIdx.x, lane = tid & 63, wave = tid >> 6;

    __shared__ __align__(16) bf16 As[64][40];
    __shared__ __align__(16) bf16 Bs[64][40];
    __shared__ int   stok[64];
    __shared__ float swgt[64];

    if (tid < 64) {
        const int s = m0 + tid;
        stok[tid] = (s < ne) ? tok_list[e * T_ + s] : -1;
        swgt[tid] = (s < ne) ? wgt_list[e * T_ + s] : 0.f;
    }
    __syncthreads();

    const int sb = base[e];
    const int ar = tid >> 2, ak = (tid & 3) * 8;
    const bool arow_ok = (m0 + ar) < ne;
    const int bn = tid & 63, bk = wave * 8;
    const float* wbase = w2 + (size_t)e * IDIM * H_ + n0 + bn;

    const int wm = wave >> 1, wn = wave & 1;
    const int q = lane >> 4, r = lane & 15;
    f32x4 acc[2][2] = {};

    for (int kb = 0; kb < IDIM / 32; ++kb) {
        __syncthreads();
        uint4 av = make_uint4(0u, 0u, 0u, 0u);
        if (arow_ok)
            av = *(const uint4*)(act + (size_t)(sb + m0 + ar) * IDIM + kb * 32 + ak);
        *(uint4*)&As[ar][ak] = av;
        {
            const float* src = wbase + (size_t)(kb * 32 + bk) * H_;
            bf16x8 pb;
            #pragma unroll
            for (int j = 0; j < 8; ++j) pb[j] = (bf16)src[(size_t)j * H_];
            *(bf16x8*)&Bs[bn][bk] = pb;
        }
        __syncthreads();
        bf16x8 a[2], b[2];
        a[0] = *(const bf16x8*)&As[wm * 32 +      r][q * 8];
        a[1] = *(const bf16x8*)&As[wm * 32 + 16 + r][q * 8];
        b[0] = *(const bf16x8*)&Bs[wn * 32 +      r][q * 8];
        b[1] = *(const bf16x8*)&Bs[wn * 32 + 16 + r][q * 8];
        #pragma unroll
        for (int im = 0; im < 2; ++im)
            #pragma unroll
            for (int in = 0; in < 2; ++in)
                acc[im][in] = __builtin_amdgcn_mfma_f32_16x16x32_bf16(a[im], b[in], acc[im][in], 0, 0, 0);
    }

    #pragma unroll
    for (int im = 0; im < 2; ++im) {
        #pragma unroll
        for (int in = 0; in < 2; ++in) {
            #pragma unroll
            for (int rg = 0; rg < 4; ++rg) {
                const int row = wm * 32 + im * 16 + q * 4 + rg;
                const int col = wn * 32 + in * 16 + r;
                if (m0 + row < ne) {
                    const int   tok = stok[row];
                    const float w   = swgt[row];
                    const float v   = w * (acc[im][in][rg] + b2[e * H_ + n0 + col]);
                    atomicAdd(&out[(size_t)tok * H_ + n0 + col], v);
                }
            }
        }
    }
}

// ---------------------------------------------------------------------------
extern "C" void kernel_launch(void* const* d_in, const int* in_sizes, int n_in,
                              void* d_out, int out_size, void* d_ws, size_t ws_size,
                              hipStream_t stream)
{
    const float* x        = (const float*)d_in[0];
    const float* norm_w   = (const float*)d_in[1];
    const float* router_w = (const float*)d_in[2];
    const float* router_b = (const float*)d_in[3];
    const float* w13      = (const float*)d_in[4];
    const float* b13      = (const float*)d_in[5];
    const float* w2       = (const float*)d_in[6];
    const float* b2       = (const float*)d_in[7];
    const float* manual_w = (const float*)d_in[8];
    const int*   layer_i  = (const int*)d_in[9];
    float* out = (float*)d_out;

    char* ws = (char*)d_ws;
    bf16*  tB       = (bf16*)ws;                               // 2 MB
    bf16*  act      = (bf16*)(ws + (2u << 20));                // 8 MB
    int*   cnt      = (int*)(ws + (10u << 20));                // 16 ints
    int*   basep    = cnt + E_;                                // 17 ints
    int*   tok_list = (int*)(ws + (10u << 20) + 256);          // 64 KB
    float* wgt_list = (float*)(ws + (10u << 20) + 256 + (64u << 10)); // 64 KB

    hipMemsetAsync(cnt, 0, E_ * sizeof(int), stream);

    k_rms_router<<<T_, 256, 0, stream>>>(x, norm_w, router_w, router_b,
                                         manual_w, layer_i, tB, out,
                                         cnt, tok_list, wgt_list);
    k_scan<<<1, 64, 0, stream>>>(cnt, basep);

    dim3 gg(IDIM / 64, T_ / 64, E_);
    k_gateup<<<gg, 256, 0, stream>>>(tB, w13, b13, cnt, basep, tok_list, act);

    dim3 gd(H_ / 64, T_ / 64, E_);
    k_down<<<gd, 256, 0, stream>>>(act, w2, b2, cnt, basep, tok_list, wgt_list, out);
}